// Round 11
// baseline (1590.525 us; speedup 1.0000x reference)
//
#include <hip/hip_runtime.h>

#define L_SEQ 100
#define E_DIM 100
#define G_DIM 192   // 3*H
#define B_TOT 4096
#define L2E   1.4426950408889634f

typedef __attribute__((ext_vector_type(8))) short bf16x8;
typedef __attribute__((ext_vector_type(4))) float f32x4;
typedef __attribute__((ext_vector_type(4))) float float4v;
typedef __attribute__((ext_vector_type(2))) float float2v;
typedef __attribute__((ext_vector_type(4))) unsigned uint4v;
typedef __attribute__((ext_vector_type(2))) unsigned uint2v;

#define MFMA16 __builtin_amdgcn_mfma_f32_16x16x32_bf16

static __device__ __forceinline__ unsigned short f2bf(float f) {
    union { float f; unsigned u; } v; v.f = f;
    unsigned r = v.u + 0x7FFFu + ((v.u >> 16) & 1u);  // RNE
    return (unsigned short)(r >> 16);
}
static __device__ __forceinline__ unsigned cvtpk(float lo, float hi) {
    unsigned r;
    asm("v_cvt_pk_bf16_f32 %0, %1, %2" : "=v"(r) : "v"(lo), "v"(hi));
    return r;
}
static __device__ __forceinline__ bf16x8 as_bf16x8(uint4v u) {
    union { uint4v u; bf16x8 h; } v; v.u = u; return v.h;
}
static __device__ __forceinline__ float rcpf_(float x) { return __builtin_amdgcn_rcpf(x); }

// raw barrier: drains LDS ops only (keeps global prefetch in flight — no vmcnt drain)
#define BAR() do { \
    asm volatile("s_waitcnt lgkmcnt(0)" ::: "memory"); \
    __builtin_amdgcn_s_barrier(); \
    asm volatile("" ::: "memory"); \
} while (0)

struct XBuf { f32x4 v[6]; f32x4 tail; };

static __device__ __forceinline__ int tmod(int c) {
    int t = c;
    if (t >= L_SEQ) t -= L_SEQ;
    if (t >= L_SEQ) t -= L_SEQ;
    if (t >= L_SEQ) t -= L_SEQ;
    return t;
}

static __device__ __forceinline__ void x_pf(
    XBuf& b, const float* __restrict__ xlane, const float* __restrict__ xrow, int c, bool g0)
{
    const int t = tmod(c);
    const float* p = xlane + t * E_DIM;
    b.v[0] = *(const f32x4*)(p);
    b.v[1] = *(const f32x4*)(p + 4);
    b.v[2] = *(const f32x4*)(p + 32);
    b.v[3] = *(const f32x4*)(p + 36);
    b.v[4] = *(const f32x4*)(p + 64);
    b.v[5] = *(const f32x4*)(p + 68);
    const f32x4 z = {0.f, 0.f, 0.f, 0.f};
    b.tail = g0 ? *(const f32x4*)(xrow + t * E_DIM + 96) : z;
}

// ti-wave: ti[c] = L2E*(x[c]@Win + bin) -> LDS ring slot c&1 + stat partials
static __device__ __forceinline__ void produce(
    XBuf& xb, const float* __restrict__ xlane, const float* __restrict__ xrow,
    int c, bool g0, float* __restrict__ tird, float* __restrict__ sltiw,
    const bf16x8 (&awin)[3][4], const float (&binq)[12])
{
    bf16x8 bx0 = as_bf16x8((uint4v){cvtpk(xb.v[0][0], xb.v[0][1]), cvtpk(xb.v[0][2], xb.v[0][3]),
                                    cvtpk(xb.v[1][0], xb.v[1][1]), cvtpk(xb.v[1][2], xb.v[1][3])});
    bf16x8 bx1 = as_bf16x8((uint4v){cvtpk(xb.v[2][0], xb.v[2][1]), cvtpk(xb.v[2][2], xb.v[2][3]),
                                    cvtpk(xb.v[3][0], xb.v[3][1]), cvtpk(xb.v[3][2], xb.v[3][3])});
    bf16x8 bx2 = as_bf16x8((uint4v){cvtpk(xb.v[4][0], xb.v[4][1]), cvtpk(xb.v[4][2], xb.v[4][3]),
                                    cvtpk(xb.v[5][0], xb.v[5][1]), cvtpk(xb.v[5][2], xb.v[5][3])});
    bf16x8 bx3 = as_bf16x8((uint4v){cvtpk(xb.tail[0], xb.tail[1]), cvtpk(xb.tail[2], xb.tail[3]),
                                    0u, 0u});
    x_pf(xb, xlane, xrow, c + 2, g0);   // refill this buffer for produce-arg c+2

    const f32x4 zero = {0.f, 0.f, 0.f, 0.f};
    f32x4 t0 = MFMA16(awin[0][0], bx0, zero, 0, 0, 0);
    f32x4 t1 = MFMA16(awin[1][0], bx0, zero, 0, 0, 0);
    f32x4 t2 = MFMA16(awin[2][0], bx0, zero, 0, 0, 0);
    t0 = MFMA16(awin[0][1], bx1, t0, 0, 0, 0);
    t1 = MFMA16(awin[1][1], bx1, t1, 0, 0, 0);
    t2 = MFMA16(awin[2][1], bx1, t2, 0, 0, 0);
    t0 = MFMA16(awin[0][2], bx2, t0, 0, 0, 0);
    t1 = MFMA16(awin[1][2], bx2, t1, 0, 0, 0);
    t2 = MFMA16(awin[2][2], bx2, t2, 0, 0, 0);
    t0 = MFMA16(awin[0][3], bx3, t0, 0, 0, 0);
    t1 = MFMA16(awin[1][3], bx3, t1, 0, 0, 0);
    t2 = MFMA16(awin[2][3], bx3, t2, 0, 0, 0);

    const int par = c & 1;
    float4v A0 = {t0[0] + binq[0], t0[1] + binq[1], t0[2] + binq[2],  t0[3] + binq[3]};
    float4v A1 = {t1[0] + binq[4], t1[1] + binq[5], t1[2] + binq[6],  t1[3] + binq[7]};
    float4v A2 = {t2[0] + binq[8], t2[1] + binq[9], t2[2] + binq[10], t2[3] + binq[11]};
    float* dst = tird + par * 3328;     // parity stride = 4*16*52 floats
    *(float4v*)(dst)     = A0;
    *(float4v*)(dst + 4) = A1;
    *(float4v*)(dst + 8) = A2;

    float s = ((A0[0] + A0[1]) + (A0[2] + A0[3])) + ((A1[0] + A1[1]) + (A1[2] + A1[3]))
            + ((A2[0] + A2[1]) + (A2[2] + A2[3]));
    float ss = 0.f;
    #pragma unroll
    for (int k2 = 0; k2 < 4; ++k2) ss = fmaf(A0[k2], A0[k2], ss);
    #pragma unroll
    for (int k2 = 0; k2 < 4; ++k2) ss = fmaf(A1[k2], A1[k2], ss);
    #pragma unroll
    for (int k2 = 0; k2 < 4; ++k2) ss = fmaf(A2[k2], A2[k2], ss);
    s  += __shfl_xor(s, 16);  s  += __shfl_xor(s, 32);
    ss += __shfl_xor(ss, 16); ss += __shfl_xor(ss, 32);
    if (g0) *(float2v*)(sltiw + par * 192) = (float2v){s, ss};
}

// 8 unique rows/block, lanes c16 and c16+8 duplicate a row -> 2 independent blocks/CU fill stalls
__global__ __launch_bounds__(512, 4) void gru_ws(
    const float* __restrict__ x,
    const float* __restrict__ Win, const float* __restrict__ bin,
    const float* __restrict__ Wh,  const float* __restrict__ bh,
    const float* __restrict__ Wfc, const float* __restrict__ bfc,
    float* __restrict__ out)
{
    __shared__ __align__(16) unsigned short hs[2][16][72];   // h ring [parity][row-slot][hdim]
    __shared__ __align__(16) float tir[2][4][16][52];        // ti ring (L2E-scaled)
    __shared__ __align__(16) float slti[2][16][12];          // ti stat partials {s,ss}/wave
    __shared__ __align__(16) float slth[2][16][12];          // th stat partials

    const int tid = threadIdx.x;
    const int wv  = tid >> 6;
    const int w   = wv & 3;
    const bool tirole = (wv >= 4);
    const int l = tid & 63, c16 = l & 15, g = l >> 4;
    const bool g0 = (g == 0);
    const int row0 = blockIdx.x * 8;          // 8 unique rows; slot c16 holds row row0 + (c16&7)

    bf16x8 awin[3][4]; float binq[12];
    bf16x8 awh[3][2];  float bhqL[12];
    const float* xrow = nullptr; const float* xlane = nullptr;

    if (tirole) {
        #pragma unroll
        for (int i = 0; i < 3; ++i)
          #pragma unroll
          for (int kt = 0; kt < 4; ++kt)
            #pragma unroll
            for (int j = 0; j < 8; ++j) {
                int k = 32 * kt + 8 * g + j;
                float v = (k < E_DIM) ? Win[k * G_DIM + 16 * (w + 4 * i) + c16] * L2E : 0.f;
                awin[i][kt][j] = (short)f2bf(v);
            }
        #pragma unroll
        for (int i = 0; i < 3; ++i)
          #pragma unroll
          for (int rr = 0; rr < 4; ++rr)
              binq[4 * i + rr] = bin[16 * (w + 4 * i) + 4 * g + rr] * L2E;
        xrow  = x + (size_t)(row0 + (c16 & 7)) * (L_SEQ * E_DIM);
        xlane = xrow + 8 * g;
    } else {
        #pragma unroll
        for (int i = 0; i < 3; ++i)
          #pragma unroll
          for (int kt = 0; kt < 2; ++kt)
            #pragma unroll
            for (int j = 0; j < 8; ++j)
                awh[i][kt][j] = (short)f2bf(Wh[(32 * kt + 8 * g + j) * G_DIM + 16 * (w + 4 * i) + c16] * L2E);
        #pragma unroll
        for (int i = 0; i < 3; ++i)
          #pragma unroll
          for (int rr = 0; rr < 4; ++rr)
              bhqL[4 * i + rr] = bh[16 * (w + 4 * i) + 4 * g + rr] * L2E;
        bf16x8 z = {0, 0, 0, 0, 0, 0, 0, 0};
        *(bf16x8*)&hs[0][c16][8 * g]      = z;
        *(bf16x8*)&hs[0][c16][32 + 8 * g] = z;
    }

    float* tird        = &tir[0][w][c16][g * 12];
    float* sltiw       = &slti[0][c16][2 * w];
    float* slthw       = &slth[0][c16][2 * w];
    const float* sltir = &slti[0][c16][0];
    const float* slthr = &slth[0][c16][0];

    float hreg[4] = {0.f, 0.f, 0.f, 0.f};

    XBuf xA, xB;
    if (tirole) {
        x_pf(xA, xlane, xrow, 0, g0);
        x_pf(xB, xlane, xrow, 1, g0);
        produce(xA, xlane, xrow, 0, g0, tird, sltiw, awin, binq);   // slot 0; refills xA for c=2
    }
    BAR();
    if (!tirole) __builtin_amdgcn_s_setprio(1);   // favor recurrent critical path (T5)

    auto HGEMM = [&](int par, float (&b)[12]) {
        bf16x8 h0 = *(const bf16x8*)&hs[par][c16][8 * g];
        bf16x8 h1 = *(const bf16x8*)&hs[par][c16][32 + 8 * g];
        const f32x4 zero = {0.f, 0.f, 0.f, 0.f};
        f32x4 t0 = MFMA16(awh[0][0], h0, zero, 0, 0, 0);
        f32x4 t1 = MFMA16(awh[1][0], h0, zero, 0, 0, 0);
        f32x4 t2 = MFMA16(awh[2][0], h0, zero, 0, 0, 0);
        t0 = MFMA16(awh[0][1], h1, t0, 0, 0, 0);
        t1 = MFMA16(awh[1][1], h1, t1, 0, 0, 0);
        t2 = MFMA16(awh[2][1], h1, t2, 0, 0, 0);
        #pragma unroll
        for (int rr = 0; rr < 4; ++rr) {
            b[rr]     = t0[rr] + bhqL[rr];
            b[4 + rr] = t1[rr] + bhqL[4 + rr];
            b[8 + rr] = t2[rr] + bhqL[8 + rr];
        }
    };
    auto HWRITE = [&](int par, float (&hn)[4]) {
        *(uint2v*)&hs[par ^ 1][c16][16 * w + 4 * g] = (uint2v){cvtpk(hn[0], hn[1]), cvtpk(hn[2], hn[3])};
    };

    // phase-1 h-wave step: gates without norm (L2E domain), ti read at step start (R8 schedule)
    auto H1 = [&](int st) {
        const int par = st & 1;
        const float* src = tird + par * 3328;
        float4v a0 = *(const float4v*)(src);
        float4v a1 = *(const float4v*)(src + 4);
        float4v a2 = *(const float4v*)(src + 8);
        float b[12];
        HGEMM(par, b);
        float hn[4];
        #pragma unroll
        for (int rr = 0; rr < 4; ++rr) {
            float er = rcpf_(1.f + __builtin_exp2f(-(a0[rr] + b[rr])));
            float zt = rcpf_(1.f + __builtin_exp2f(-(a1[rr] + b[4 + rr])));
            float uL = fmaf(er, b[8 + rr], a2[rr]);
            float tn = fmaf(2.f, rcpf_(1.f + __builtin_exp2f(-(uL + uL))), -1.f);
            hn[rr] = fmaf(zt, hreg[rr] - tn, tn);
            hreg[rr] = hn[rr];
        }
        HWRITE(par, hn);
    };

    // ---------------- phase 1: 1 barrier/step ----------------
    #pragma unroll 1
    for (int s = 0; s < L_SEQ; s += 2) {
        if (tirole) produce(xB, xlane, xrow, s + 1, g0, tird, sltiw, awin, binq);
        else        H1(s);
        BAR();
        if (tirole) produce(xA, xlane, xrow, s + 2, g0, tird, sltiw, awin, binq);
        else        H1(s + 1);
        BAR();
    }

    // phase-2 h-wave step: ti + ti-stats read at step start; th-stats exchange w/ mid-BAR
    auto H2 = [&](int st) {
        const int par = st & 1;
        const float* src = tird + par * 3328;
        float4v a0 = *(const float4v*)(src);
        float4v a1 = *(const float4v*)(src + 4);
        float4v a2 = *(const float4v*)(src + 8);
        const float* ip = sltir + par * 192;
        float4v r0 = *(const float4v*)(ip);
        float4v r1 = *(const float4v*)(ip + 4);
        float Sti  = (r0[0] + r0[2]) + (r1[0] + r1[2]);
        float SSti = (r0[1] + r0[3]) + (r1[1] + r1[3]);
        float mti  = Sti * (1.f / G_DIM);
        float vti  = (SSti - (float)G_DIM * mti * mti) * (1.f / (G_DIM - 1));
        float rtiF = __builtin_amdgcn_rsqf(fmaxf(vti, 1e-24f)) * L2E;
        float cFti = mti * rtiF;

        float b[12];
        HGEMM(par, b);
        float sb = 0.f, ssb = 0.f;
        #pragma unroll
        for (int k2 = 0; k2 < 12; ++k2) { sb += b[k2]; ssb = fmaf(b[k2], b[k2], ssb); }
        sb  += __shfl_xor(sb, 16);  sb  += __shfl_xor(sb, 32);
        ssb += __shfl_xor(ssb, 16); ssb += __shfl_xor(ssb, 32);
        if (g0) *(float2v*)(slthw + par * 192) = (float2v){sb, ssb};
        BAR();   // mid: th partials visible
        const float* sp = slthr + par * 192;
        float4v q0 = *(const float4v*)(sp);
        float4v q1 = *(const float4v*)(sp + 4);
        float S  = (q0[0] + q0[2]) + (q1[0] + q1[2]);
        float SS = (q0[1] + q0[3]) + (q1[1] + q1[3]);
        float m  = S * (1.f / G_DIM);
        float var = (SS - (float)G_DIM * m * m) * (1.f / (G_DIM - 1));
        float rthF = __builtin_amdgcn_rsqf(fmaxf(var, 1e-24f)) * L2E;
        float chF  = m * rthF;
        float hn[4];
        #pragma unroll
        for (int rr = 0; rr < 4; ++rr) {
            float ntr = fmaf(a0[rr], rtiF, -cFti);
            float ntz = fmaf(a1[rr], rtiF, -cFti);
            float ntn = fmaf(a2[rr], rtiF, -cFti);
            float nhr = fmaf(b[rr],     rthF, -chF);
            float nhz = fmaf(b[4 + rr], rthF, -chF);
            float nhn = fmaf(b[8 + rr], rthF, -chF);
            float er = rcpf_(1.f + __builtin_exp2f(-(ntr + nhr)));
            float zt = rcpf_(1.f + __builtin_exp2f(-(ntz + nhz)));
            float uL = fmaf(er, nhn, ntn);
            float tn = fmaf(2.f, rcpf_(1.f + __builtin_exp2f(-(uL + uL))), -1.f);
            hn[rr] = fmaf(zt, hreg[rr] - tn, tn);
            hreg[rr] = hn[rr];
        }
        HWRITE(par, hn);
    };

    // ---------------- phase 2: 2 barriers/step ----------------
    #pragma unroll 1
    for (int s = L_SEQ; s < 2 * L_SEQ; s += 2) {
        if (tirole) { produce(xB, xlane, xrow, s + 1, g0, tird, sltiw, awin, binq); BAR(); }
        else        H2(s);           // contains the mid-BAR
        BAR();
        if (tirole) { produce(xA, xlane, xrow, s + 2, g0, tird, sltiw, awin, binq); BAR(); }
        else        H2(s + 1);
        BAR();
    }

    // ---------------- epilogue: out = h @ W_fc + b_fc ----------------
    if (!tirole) {
        float po0 = 0.f, po1 = 0.f;
        #pragma unroll
        for (int rr = 0; rr < 4; ++rr) {
            int c = 16 * w + 4 * g + rr;
            po0 = fmaf(hreg[rr], Wfc[2 * c],     po0);
            po1 = fmaf(hreg[rr], Wfc[2 * c + 1], po1);
        }
        po0 += __shfl_xor(po0, 16); po0 += __shfl_xor(po0, 32);
        po1 += __shfl_xor(po1, 16); po1 += __shfl_xor(po1, 32);
        if (g0) *(float2v*)(slthw) = (float2v){po0, po1};
    }
    BAR();
    if (tid < 8) {   // rows 8..15 are duplicates
        const float* sp = &slth[0][tid][0];
        float4v q0 = *(const float4v*)(sp);
        float4v q1 = *(const float4v*)(sp + 4);
        out[(row0 + tid) * 2 + 0] = (q0[0] + q0[2]) + (q1[0] + q1[2]) + bfc[0];
        out[(row0 + tid) * 2 + 1] = (q0[1] + q0[3]) + (q1[1] + q1[3]) + bfc[1];
    }
}

extern "C" void kernel_launch(void* const* d_in, const int* in_sizes, int n_in,
                              void* d_out, int out_size, void* d_ws, size_t ws_size,
                              hipStream_t stream) {
    const float* x   = (const float*)d_in[0];
    const float* Win = (const float*)d_in[1];
    const float* bin = (const float*)d_in[2];
    const float* Wh  = (const float*)d_in[3];
    const float* bh  = (const float*)d_in[4];
    const float* Wfc = (const float*)d_in[5];
    const float* bfc = (const float*)d_in[6];
    float* out = (float*)d_out;
    gru_ws<<<dim3(B_TOT / 8), dim3(512), 0, stream>>>(
        x, Win, bin, Wh, bh, Wfc, bfc, out);
}

// Round 12
// 846.019 us; speedup vs baseline: 1.8800x; 1.8800x over previous
//
#include <hip/hip_runtime.h>

#define L_SEQ 100
#define E_DIM 100
#define G_DIM 192   // 3*H
#define B_TOT 4096
#define L2E   1.4426950408889634f

typedef __attribute__((ext_vector_type(8))) short bf16x8;
typedef __attribute__((ext_vector_type(4))) float f32x4;
typedef __attribute__((ext_vector_type(4))) float float4v;
typedef __attribute__((ext_vector_type(2))) float float2v;
typedef __attribute__((ext_vector_type(4))) unsigned uint4v;
typedef __attribute__((ext_vector_type(2))) unsigned uint2v;

#define MFMA16 __builtin_amdgcn_mfma_f32_16x16x32_bf16

static __device__ __forceinline__ unsigned short f2bf(float f) {
    union { float f; unsigned u; } v; v.f = f;
    unsigned r = v.u + 0x7FFFu + ((v.u >> 16) & 1u);  // RNE
    return (unsigned short)(r >> 16);
}
static __device__ __forceinline__ unsigned cvtpk(float lo, float hi) {
    unsigned r;
    asm("v_cvt_pk_bf16_f32 %0, %1, %2" : "=v"(r) : "v"(lo), "v"(hi));
    return r;
}
static __device__ __forceinline__ bf16x8 as_bf16x8(uint4v u) {
    union { uint4v u; bf16x8 h; } v; v.u = u; return v.h;
}
static __device__ __forceinline__ float rcpf_(float x) { return __builtin_amdgcn_rcpf(x); }

// raw barrier: drains LDS ops only (keeps global prefetch in flight — no vmcnt drain)
#define BAR() do { \
    asm volatile("s_waitcnt lgkmcnt(0)" ::: "memory"); \
    __builtin_amdgcn_s_barrier(); \
    asm volatile("" ::: "memory"); \
} while (0)

struct XBuf { f32x4 v[6]; f32x4 tail; };

static __device__ __forceinline__ int tmod(int c) {
    int t = c;
    if (t >= L_SEQ) t -= L_SEQ;
    if (t >= L_SEQ) t -= L_SEQ;
    if (t >= L_SEQ) t -= L_SEQ;
    return t;
}

static __device__ __forceinline__ void x_pf(
    XBuf& b, const float* __restrict__ xlane, const float* __restrict__ xrow, int c, bool g0)
{
    const int t = tmod(c);
    const float* p = xlane + t * E_DIM;
    b.v[0] = *(const f32x4*)(p);
    b.v[1] = *(const f32x4*)(p + 4);
    b.v[2] = *(const f32x4*)(p + 32);
    b.v[3] = *(const f32x4*)(p + 36);
    b.v[4] = *(const f32x4*)(p + 64);
    b.v[5] = *(const f32x4*)(p + 68);
    const f32x4 z = {0.f, 0.f, 0.f, 0.f};
    b.tail = g0 ? *(const f32x4*)(xrow + t * E_DIM + 96) : z;
}

// ti-wave: ti[c] = L2E*(x[c]@Win + bin) -> LDS ring slot c&1 + stat partials
static __device__ __forceinline__ void produce(
    XBuf& xb, const float* __restrict__ xlane, const float* __restrict__ xrow,
    int c, bool g0, float* __restrict__ tird, float* __restrict__ sltiw,
    const bf16x8 (&awin)[3][4], const float (&binq)[12])
{
    bf16x8 bx0 = as_bf16x8((uint4v){cvtpk(xb.v[0][0], xb.v[0][1]), cvtpk(xb.v[0][2], xb.v[0][3]),
                                    cvtpk(xb.v[1][0], xb.v[1][1]), cvtpk(xb.v[1][2], xb.v[1][3])});
    bf16x8 bx1 = as_bf16x8((uint4v){cvtpk(xb.v[2][0], xb.v[2][1]), cvtpk(xb.v[2][2], xb.v[2][3]),
                                    cvtpk(xb.v[3][0], xb.v[3][1]), cvtpk(xb.v[3][2], xb.v[3][3])});
    bf16x8 bx2 = as_bf16x8((uint4v){cvtpk(xb.v[4][0], xb.v[4][1]), cvtpk(xb.v[4][2], xb.v[4][3]),
                                    cvtpk(xb.v[5][0], xb.v[5][1]), cvtpk(xb.v[5][2], xb.v[5][3])});
    bf16x8 bx3 = as_bf16x8((uint4v){cvtpk(xb.tail[0], xb.tail[1]), cvtpk(xb.tail[2], xb.tail[3]),
                                    0u, 0u});
    x_pf(xb, xlane, xrow, c + 2, g0);   // refill this buffer for produce-arg c+2

    const f32x4 zero = {0.f, 0.f, 0.f, 0.f};
    f32x4 t0 = MFMA16(awin[0][0], bx0, zero, 0, 0, 0);
    f32x4 t1 = MFMA16(awin[1][0], bx0, zero, 0, 0, 0);
    f32x4 t2 = MFMA16(awin[2][0], bx0, zero, 0, 0, 0);
    t0 = MFMA16(awin[0][1], bx1, t0, 0, 0, 0);
    t1 = MFMA16(awin[1][1], bx1, t1, 0, 0, 0);
    t2 = MFMA16(awin[2][1], bx1, t2, 0, 0, 0);
    t0 = MFMA16(awin[0][2], bx2, t0, 0, 0, 0);
    t1 = MFMA16(awin[1][2], bx2, t1, 0, 0, 0);
    t2 = MFMA16(awin[2][2], bx2, t2, 0, 0, 0);
    t0 = MFMA16(awin[0][3], bx3, t0, 0, 0, 0);
    t1 = MFMA16(awin[1][3], bx3, t1, 0, 0, 0);
    t2 = MFMA16(awin[2][3], bx3, t2, 0, 0, 0);

    const int par = c & 1;
    float4v A0 = {t0[0] + binq[0], t0[1] + binq[1], t0[2] + binq[2],  t0[3] + binq[3]};
    float4v A1 = {t1[0] + binq[4], t1[1] + binq[5], t1[2] + binq[6],  t1[3] + binq[7]};
    float4v A2 = {t2[0] + binq[8], t2[1] + binq[9], t2[2] + binq[10], t2[3] + binq[11]};
    float* dst = tird + par * 3328;     // parity stride = 4*16*52 floats
    *(float4v*)(dst)     = A0;
    *(float4v*)(dst + 4) = A1;
    *(float4v*)(dst + 8) = A2;

    float s = ((A0[0] + A0[1]) + (A0[2] + A0[3])) + ((A1[0] + A1[1]) + (A1[2] + A1[3]))
            + ((A2[0] + A2[1]) + (A2[2] + A2[3]));
    float ss = 0.f;
    #pragma unroll
    for (int k2 = 0; k2 < 4; ++k2) ss = fmaf(A0[k2], A0[k2], ss);
    #pragma unroll
    for (int k2 = 0; k2 < 4; ++k2) ss = fmaf(A1[k2], A1[k2], ss);
    #pragma unroll
    for (int k2 = 0; k2 < 4; ++k2) ss = fmaf(A2[k2], A2[k2], ss);
    s  += __shfl_xor(s, 16);  s  += __shfl_xor(s, 32);
    ss += __shfl_xor(ss, 16); ss += __shfl_xor(ss, 32);
    if (g0) *(float2v*)(sltiw + par * 192) = (float2v){s, ss};
}

__global__ __launch_bounds__(512, 1) void gru_ws(
    const float* __restrict__ x,
    const float* __restrict__ Win, const float* __restrict__ bin,
    const float* __restrict__ Wh,  const float* __restrict__ bh,
    const float* __restrict__ Wfc, const float* __restrict__ bfc,
    float* __restrict__ out)
{
    __shared__ __align__(16) unsigned short hs[2][16][72];   // h ring [parity][row][hdim]
    __shared__ __align__(16) float tir[2][4][16][52];        // ti ring (L2E-scaled)
    __shared__ __align__(16) float slti[2][16][12];          // ti stat partials {s,ss}/wave
    __shared__ __align__(16) float slth[2][16][12];          // epilogue scratch

    const int tid = threadIdx.x;
    const int wv  = tid >> 6;
    const int w   = wv & 3;
    const bool tirole = (wv >= 4);
    const int l = tid & 63, c16 = l & 15, g = l >> 4;
    const bool g0 = (g == 0);
    const int row0 = blockIdx.x * 16;

    bf16x8 awin[3][4]; float binq[12];
    bf16x8 awhF[12][2]; float bhAll[48];
    const float* xrow = nullptr; const float* xlane = nullptr;

    if (tirole) {
        #pragma unroll
        for (int i = 0; i < 3; ++i)
          #pragma unroll
          for (int kt = 0; kt < 4; ++kt)
            #pragma unroll
            for (int j = 0; j < 8; ++j) {
                int k = 32 * kt + 8 * g + j;
                float v = (k < E_DIM) ? Win[k * G_DIM + 16 * (w + 4 * i) + c16] * L2E : 0.f;
                awin[i][kt][j] = (short)f2bf(v);
            }
        #pragma unroll
        for (int i = 0; i < 3; ++i)
          #pragma unroll
          for (int rr = 0; rr < 4; ++rr)
              binq[4 * i + rr] = bin[16 * (w + 4 * i) + 4 * g + rr] * L2E;
        xrow  = x + (size_t)(row0 + c16) * (L_SEQ * E_DIM);
        xlane = xrow + 8 * g;
    } else {
        // full Wh^T fragment set: all 12 n-tiles (redundant GEMM -> barrier-free stats)
        #pragma unroll
        for (int n = 0; n < 12; ++n)
          #pragma unroll
          for (int kt = 0; kt < 2; ++kt)
            #pragma unroll
            for (int j = 0; j < 8; ++j)
                awhF[n][kt][j] = (short)f2bf(Wh[(32 * kt + 8 * g + j) * G_DIM + 16 * n + c16] * L2E);
        #pragma unroll
        for (int n = 0; n < 12; ++n)
          #pragma unroll
          for (int rr = 0; rr < 4; ++rr)
              bhAll[4 * n + rr] = bh[16 * n + 4 * g + rr] * L2E;
        bf16x8 z = {0, 0, 0, 0, 0, 0, 0, 0};
        *(bf16x8*)&hs[0][c16][8 * g]      = z;
        *(bf16x8*)&hs[0][c16][32 + 8 * g] = z;
    }

    float* tird        = &tir[0][w][c16][g * 12];
    float* sltiw       = &slti[0][c16][2 * w];
    const float* sltir = &slti[0][c16][0];
    float* slthw       = &slth[0][c16][2 * w];

    float hreg[4] = {0.f, 0.f, 0.f, 0.f};

    XBuf xA, xB;
    if (tirole) {
        x_pf(xA, xlane, xrow, 0, g0);
        x_pf(xB, xlane, xrow, 1, g0);
        produce(xA, xlane, xrow, 0, g0, tird, sltiw, awin, binq);   // slot 0; refills xA for c=2
    }
    BAR();
    if (!tirole) __builtin_amdgcn_s_setprio(1);   // favor recurrent critical path (T5)

    auto HWRITE = [&](int par, float (&hn)[4]) {
        *(uint2v*)&hs[par ^ 1][c16][16 * w + 4 * g] = (uint2v){cvtpk(hn[0], hn[1]), cvtpk(hn[2], hn[3])};
    };

    // phase-1 h-wave step: full GEMM, capture own 3 tiles, gates without norm
    auto H1 = [&](int st) {
        const int par = st & 1;
        const float* src = tird + par * 3328;
        float4v a0 = *(const float4v*)(src);
        float4v a1 = *(const float4v*)(src + 4);
        float4v a2 = *(const float4v*)(src + 8);
        bf16x8 h0 = *(const bf16x8*)&hs[par][c16][8 * g];
        bf16x8 h1 = *(const bf16x8*)&hs[par][c16][32 + 8 * g];
        const f32x4 zero = {0.f, 0.f, 0.f, 0.f};
        float bq[12] = {};
        #pragma unroll
        for (int half = 0; half < 2; ++half) {
            f32x4 acc[6];
            #pragma unroll
            for (int n6 = 0; n6 < 6; ++n6)
                acc[n6] = MFMA16(awhF[half * 6 + n6][0], h0, zero, 0, 0, 0);
            #pragma unroll
            for (int n6 = 0; n6 < 6; ++n6)
                acc[n6] = MFMA16(awhF[half * 6 + n6][1], h1, acc[n6], 0, 0, 0);
            #pragma unroll
            for (int n6 = 0; n6 < 6; ++n6) {
                const int n = half * 6 + n6;
                #pragma unroll
                for (int rr = 0; rr < 4; ++rr) {
                    if (n == w)          bq[rr]     = acc[n6][rr] + bhAll[4 * n + rr];
                    else if (n == w + 4) bq[4 + rr] = acc[n6][rr] + bhAll[4 * n + rr];
                    else if (n == w + 8) bq[8 + rr] = acc[n6][rr] + bhAll[4 * n + rr];
                }
            }
        }
        float hn[4];
        #pragma unroll
        for (int rr = 0; rr < 4; ++rr) {
            float er = rcpf_(1.f + __builtin_exp2f(-(a0[rr] + bq[rr])));
            float zt = rcpf_(1.f + __builtin_exp2f(-(a1[rr] + bq[4 + rr])));
            float uL = fmaf(er, bq[8 + rr], a2[rr]);
            float tn = fmaf(2.f, rcpf_(1.f + __builtin_exp2f(-(uL + uL))), -1.f);
            hn[rr] = fmaf(zt, hreg[rr] - tn, tn);
            hreg[rr] = hn[rr];
        }
        HWRITE(par, hn);
    };

    // ---------------- phase 1: 1 barrier/step ----------------
    #pragma unroll 1
    for (int s = 0; s < L_SEQ; s += 2) {
        if (tirole) produce(xB, xlane, xrow, s + 1, g0, tird, sltiw, awin, binq);
        else        H1(s);
        BAR();
        if (tirole) produce(xA, xlane, xrow, s + 2, g0, tird, sltiw, awin, binq);
        else        H1(s + 1);
        BAR();
    }

    // phase-2 h-wave step: full GEMM + in-wave stats (no mid-barrier, no LDS partials)
    auto H2 = [&](int st) {
        const int par = st & 1;
        const float* src = tird + par * 3328;
        float4v a0 = *(const float4v*)(src);
        float4v a1 = *(const float4v*)(src + 4);
        float4v a2 = *(const float4v*)(src + 8);
        const float* ip = sltir + par * 192;
        float4v r0 = *(const float4v*)(ip);
        float4v r1 = *(const float4v*)(ip + 4);
        float Sti  = (r0[0] + r0[2]) + (r1[0] + r1[2]);
        float SSti = (r0[1] + r0[3]) + (r1[1] + r1[3]);
        float mti  = Sti * (1.f / G_DIM);
        float vti  = (SSti - (float)G_DIM * mti * mti) * (1.f / (G_DIM - 1));
        float rtiF = __builtin_amdgcn_rsqf(fmaxf(vti, 1e-24f)) * L2E;
        float cFti = mti * rtiF;

        bf16x8 h0 = *(const bf16x8*)&hs[par][c16][8 * g];
        bf16x8 h1 = *(const bf16x8*)&hs[par][c16][32 + 8 * g];
        const f32x4 zero = {0.f, 0.f, 0.f, 0.f};
        float bq[12] = {};
        float S = 0.f, SS = 0.f;
        #pragma unroll
        for (int half = 0; half < 2; ++half) {
            f32x4 acc[6];
            #pragma unroll
            for (int n6 = 0; n6 < 6; ++n6)
                acc[n6] = MFMA16(awhF[half * 6 + n6][0], h0, zero, 0, 0, 0);
            #pragma unroll
            for (int n6 = 0; n6 < 6; ++n6)
                acc[n6] = MFMA16(awhF[half * 6 + n6][1], h1, acc[n6], 0, 0, 0);
            #pragma unroll
            for (int n6 = 0; n6 < 6; ++n6) {
                const int n = half * 6 + n6;
                #pragma unroll
                for (int rr = 0; rr < 4; ++rr) {
                    float v = acc[n6][rr] + bhAll[4 * n + rr];
                    S += v;
                    SS = fmaf(v, v, SS);
                    if (n == w)          bq[rr]     = v;
                    else if (n == w + 4) bq[4 + rr] = v;
                    else if (n == w + 8) bq[8 + rr] = v;
                }
            }
        }
        // row stats: in-lane 48-sum done; finish across the 4 g-groups
        S  += __shfl_xor(S, 16);  S  += __shfl_xor(S, 32);
        SS += __shfl_xor(SS, 16); SS += __shfl_xor(SS, 32);
        float m   = S * (1.f / G_DIM);
        float var = (SS - (float)G_DIM * m * m) * (1.f / (G_DIM - 1));
        float rthF = __builtin_amdgcn_rsqf(fmaxf(var, 1e-24f)) * L2E;
        float chF  = m * rthF;

        float hn[4];
        #pragma unroll
        for (int rr = 0; rr < 4; ++rr) {
            float ntr = fmaf(a0[rr], rtiF, -cFti);
            float ntz = fmaf(a1[rr], rtiF, -cFti);
            float ntn = fmaf(a2[rr], rtiF, -cFti);
            float nhr = fmaf(bq[rr],     rthF, -chF);
            float nhz = fmaf(bq[4 + rr], rthF, -chF);
            float nhn = fmaf(bq[8 + rr], rthF, -chF);
            float er = rcpf_(1.f + __builtin_exp2f(-(ntr + nhr)));
            float zt = rcpf_(1.f + __builtin_exp2f(-(ntz + nhz)));
            float uL = fmaf(er, nhn, ntn);
            float tn = fmaf(2.f, rcpf_(1.f + __builtin_exp2f(-(uL + uL))), -1.f);
            hn[rr] = fmaf(zt, hreg[rr] - tn, tn);
            hreg[rr] = hn[rr];
        }
        HWRITE(par, hn);
    };

    // ---------------- phase 2: 1 barrier/step (mid-barrier eliminated) ----------------
    #pragma unroll 1
    for (int s = L_SEQ; s < 2 * L_SEQ; s += 2) {
        if (tirole) produce(xB, xlane, xrow, s + 1, g0, tird, sltiw, awin, binq);
        else        H2(s);
        BAR();
        if (tirole) produce(xA, xlane, xrow, s + 2, g0, tird, sltiw, awin, binq);
        else        H2(s + 1);
        BAR();
    }

    // ---------------- epilogue: out = h @ W_fc + b_fc ----------------
    if (!tirole) {
        float po0 = 0.f, po1 = 0.f;
        #pragma unroll
        for (int rr = 0; rr < 4; ++rr) {
            int c = 16 * w + 4 * g + rr;
            po0 = fmaf(hreg[rr], Wfc[2 * c],     po0);
            po1 = fmaf(hreg[rr], Wfc[2 * c + 1], po1);
        }
        po0 += __shfl_xor(po0, 16); po0 += __shfl_xor(po0, 32);
        po1 += __shfl_xor(po1, 16); po1 += __shfl_xor(po1, 32);
        if (g0) *(float2v*)(slthw) = (float2v){po0, po1};
    }
    BAR();
    if (tid < 16) {
        const float* sp = &slth[0][tid][0];
        float4v q0 = *(const float4v*)(sp);
        float4v q1 = *(const float4v*)(sp + 4);
        out[(row0 + tid) * 2 + 0] = (q0[0] + q0[2]) + (q1[0] + q1[2]) + bfc[0];
        out[(row0 + tid) * 2 + 1] = (q0[1] + q0[3]) + (q1[1] + q1[3]) + bfc[1];
    }
}

extern "C" void kernel_launch(void* const* d_in, const int* in_sizes, int n_in,
                              void* d_out, int out_size, void* d_ws, size_t ws_size,
                              hipStream_t stream) {
    const float* x   = (const float*)d_in[0];
    const float* Win = (const float*)d_in[1];
    const float* bin = (const float*)d_in[2];
    const float* Wh  = (const float*)d_in[3];
    const float* bh  = (const float*)d_in[4];
    const float* Wfc = (const float*)d_in[5];
    const float* bfc = (const float*)d_in[6];
    float* out = (float*)d_out;
    gru_ws<<<dim3(B_TOT / 16), dim3(512), 0, stream>>>(
        x, Win, bin, Wh, bh, Wfc, bfc, out);
}

// Round 14
// 432.659 us; speedup vs baseline: 3.6762x; 1.9554x over previous
//
#include <hip/hip_runtime.h>

#define L_SEQ 100
#define E_DIM 100
#define G_DIM 192   // 3*H
#define B_TOT 4096

typedef __attribute__((ext_vector_type(8))) short bf16x8;
typedef __attribute__((ext_vector_type(4))) float f32x4;
typedef __attribute__((ext_vector_type(4))) float float4v;
typedef __attribute__((ext_vector_type(2))) float float2v;
typedef __attribute__((ext_vector_type(4))) unsigned uint4v;
typedef __attribute__((ext_vector_type(2))) unsigned uint2v;
typedef __attribute__((ext_vector_type(4))) unsigned short ushort4v;

#define MFMA16 __builtin_amdgcn_mfma_f32_16x16x32_bf16

static __device__ __forceinline__ unsigned short f2bf(float f) {
    union { float f; unsigned u; } v; v.f = f;
    unsigned r = v.u + 0x7FFFu + ((v.u >> 16) & 1u);  // RNE
    return (unsigned short)(r >> 16);
}
static __device__ __forceinline__ float bf2f(unsigned short u) {
    union { unsigned u; float f; } v; v.u = ((unsigned)u) << 16;
    return v.f;
}
static __device__ __forceinline__ unsigned cvtpk(float lo, float hi) {
    unsigned r;
    asm("v_cvt_pk_bf16_f32 %0, %1, %2" : "=v"(r) : "v"(lo), "v"(hi));
    return r;
}
static __device__ __forceinline__ bf16x8 as_bf16x8(uint4v u) {
    union { uint4v u; bf16x8 h; } v; v.u = u; return v.h;
}
static __device__ __forceinline__ float rcpf_(float x) { return __builtin_amdgcn_rcpf(x); }

// raw barrier: drains LDS ops only (keeps global prefetch in flight — no vmcnt drain)
#define BAR() do { \
    asm volatile("s_waitcnt lgkmcnt(0)" ::: "memory"); \
    __builtin_amdgcn_s_barrier(); \
    asm volatile("" ::: "memory"); \
} while (0)

struct XBuf { f32x4 v[6]; f32x4 tail; };

static __device__ __forceinline__ int tmod(int c) {
    int t = c;
    if (t >= L_SEQ) t -= L_SEQ;
    if (t >= L_SEQ) t -= L_SEQ;
    if (t >= L_SEQ) t -= L_SEQ;
    return t;
}

static __device__ __forceinline__ void x_pf(
    XBuf& b, const float* __restrict__ xlane, const float* __restrict__ xrow, int c, bool g0)
{
    const int t = tmod(c);
    const float* p = xlane + t * E_DIM;
    b.v[0] = *(const f32x4*)(p);
    b.v[1] = *(const f32x4*)(p + 4);
    b.v[2] = *(const f32x4*)(p + 32);
    b.v[3] = *(const f32x4*)(p + 36);
    b.v[4] = *(const f32x4*)(p + 64);
    b.v[5] = *(const f32x4*)(p + 68);
    const f32x4 z = {0.f, 0.f, 0.f, 0.f};
    b.tail = g0 ? *(const f32x4*)(xrow + t * E_DIM + 96) : z;
}

// ti-wave: compute ti[c] = x[c]@Win + bin, write to LDS ring slot c&1 + stat partials
static __device__ __forceinline__ void produce(
    XBuf& xb, const float* __restrict__ xlane, const float* __restrict__ xrow,
    int c, bool g0, float* __restrict__ tird, float* __restrict__ sltiw,
    const bf16x8 (&awin)[3][4], const float (&binq)[12])
{
    bf16x8 bx0 = as_bf16x8((uint4v){cvtpk(xb.v[0][0], xb.v[0][1]), cvtpk(xb.v[0][2], xb.v[0][3]),
                                    cvtpk(xb.v[1][0], xb.v[1][1]), cvtpk(xb.v[1][2], xb.v[1][3])});
    bf16x8 bx1 = as_bf16x8((uint4v){cvtpk(xb.v[2][0], xb.v[2][1]), cvtpk(xb.v[2][2], xb.v[2][3]),
                                    cvtpk(xb.v[3][0], xb.v[3][1]), cvtpk(xb.v[3][2], xb.v[3][3])});
    bf16x8 bx2 = as_bf16x8((uint4v){cvtpk(xb.v[4][0], xb.v[4][1]), cvtpk(xb.v[4][2], xb.v[4][3]),
                                    cvtpk(xb.v[5][0], xb.v[5][1]), cvtpk(xb.v[5][2], xb.v[5][3])});
    bf16x8 bx3 = as_bf16x8((uint4v){cvtpk(xb.tail[0], xb.tail[1]), cvtpk(xb.tail[2], xb.tail[3]),
                                    0u, 0u});
    x_pf(xb, xlane, xrow, c + 2, g0);   // refill this buffer for produce-arg c+2

    const f32x4 zero = {0.f, 0.f, 0.f, 0.f};
    f32x4 t0 = MFMA16(awin[0][0], bx0, zero, 0, 0, 0);
    f32x4 t1 = MFMA16(awin[1][0], bx0, zero, 0, 0, 0);
    f32x4 t2 = MFMA16(awin[2][0], bx0, zero, 0, 0, 0);
    t0 = MFMA16(awin[0][1], bx1, t0, 0, 0, 0);
    t1 = MFMA16(awin[1][1], bx1, t1, 0, 0, 0);
    t2 = MFMA16(awin[2][1], bx1, t2, 0, 0, 0);
    t0 = MFMA16(awin[0][2], bx2, t0, 0, 0, 0);
    t1 = MFMA16(awin[1][2], bx2, t1, 0, 0, 0);
    t2 = MFMA16(awin[2][2], bx2, t2, 0, 0, 0);
    t0 = MFMA16(awin[0][3], bx3, t0, 0, 0, 0);
    t1 = MFMA16(awin[1][3], bx3, t1, 0, 0, 0);
    t2 = MFMA16(awin[2][3], bx3, t2, 0, 0, 0);

    const int par = c & 1;
    float4v A0 = {t0[0] + binq[0], t0[1] + binq[1], t0[2] + binq[2],  t0[3] + binq[3]};
    float4v A1 = {t1[0] + binq[4], t1[1] + binq[5], t1[2] + binq[6],  t1[3] + binq[7]};
    float4v A2 = {t2[0] + binq[8], t2[1] + binq[9], t2[2] + binq[10], t2[3] + binq[11]};
    float* dst = tird + par * 3328;     // parity stride = 4*16*52 floats
    *(float4v*)(dst)     = A0;
    *(float4v*)(dst + 4) = A1;
    *(float4v*)(dst + 8) = A2;

    float s = ((A0[0] + A0[1]) + (A0[2] + A0[3])) + ((A1[0] + A1[1]) + (A1[2] + A1[3]))
            + ((A2[0] + A2[1]) + (A2[2] + A2[3]));
    float ss = 0.f;
    #pragma unroll
    for (int k2 = 0; k2 < 4; ++k2) ss = fmaf(A0[k2], A0[k2], ss);
    #pragma unroll
    for (int k2 = 0; k2 < 4; ++k2) ss = fmaf(A1[k2], A1[k2], ss);
    #pragma unroll
    for (int k2 = 0; k2 < 4; ++k2) ss = fmaf(A2[k2], A2[k2], ss);
    s  += __shfl_xor(s, 16);  s  += __shfl_xor(s, 32);
    ss += __shfl_xor(ss, 16); ss += __shfl_xor(ss, 32);
    if (g0) *(float2v*)(sltiw + par * 192) = (float2v){s, ss};
}

__global__ __launch_bounds__(512, 1) void gru_ws(
    const float* __restrict__ x,
    const float* __restrict__ Win, const float* __restrict__ bin,
    const float* __restrict__ Wh,  const float* __restrict__ bh,
    const float* __restrict__ Wfc, const float* __restrict__ bfc,
    float* __restrict__ out)
{
    __shared__ __align__(16) unsigned short hs[2][16][72];   // h ring [parity][row][hdim]
    __shared__ __align__(16) float tir[2][4][16][52];        // ti ring
    __shared__ __align__(16) float slti[2][16][12];          // ti stat partials {s,ss}/wave
    __shared__ __align__(16) float slth[2][16][12];          // epilogue scratch
    __shared__ __align__(16) float Ms[64][65];               // Gram M = Wh·Wh^T
    __shared__ __align__(16) float wsumS[64];                // rowsum(Wh)
    __shared__ __align__(16) float vS[64];                   // v = Wh·bh
    __shared__ float sbhS[2];                                // {sum(bh), sum(bh^2)}

    const int tid = threadIdx.x;
    const int wv  = tid >> 6;
    const int w   = wv & 3;
    const bool tirole = (wv >= 4);
    const int l = tid & 63, c16 = l & 15, g = l >> 4;
    const bool g0 = (g == 0);
    const int row0 = blockIdx.x * 16;

    // ---------------- prologue: M = Wh Wh^T, rowsum(Wh), v = Wh·bh, bh scalars ----------------
    {
        #pragma unroll 1
        for (int e8 = 0; e8 < 8; ++e8) {
            int e = (tid << 3) + e8;
            int kk = e >> 6, dd = e & 63;
            const float* wk = Wh + kk * G_DIM;
            const float* wd = Wh + dd * G_DIM;
            float acc = 0.f;
            #pragma unroll 4
            for (int c = 0; c < G_DIM; c += 4) {
                float4v a = *(const float4v*)(wk + c);
                float4v b = *(const float4v*)(wd + c);
                #pragma unroll
                for (int q = 0; q < 4; ++q) acc = fmaf(a[q], b[q], acc);
            }
            Ms[kk][dd] = acc;
        }
        if (tid < 64) {
            const float* wr = Wh + tid * G_DIM;
            float s = 0.f, sv = 0.f;
            #pragma unroll 4
            for (int c = 0; c < G_DIM; ++c) {
                s += wr[c];
                sv = fmaf(wr[c], bh[c], sv);
            }
            wsumS[tid] = s;
            vS[tid] = sv;
        }
        if (tid == 64) {
            float sb = 0.f, sq = 0.f;
            #pragma unroll 4
            for (int c = 0; c < G_DIM; ++c) {
                sb += bh[c];
                sq = fmaf(bh[c], bh[c], sq);
            }
            sbhS[0] = sb;
            sbhS[1] = sq;
        }
    }
    BAR();

    bf16x8 awin[3][4]; float binq[12];
    bf16x8 awh[3][2];  float bhq[12];
    bf16x8 awm[4][2];  float wsumq[16];
    f32x4 vC0, vC1, vC2, vC3;
    float sum_bh = 0.f, ssq_bh = 0.f;
    const float* xrow = nullptr; const float* xlane = nullptr;

    if (tirole) {
        #pragma unroll
        for (int i = 0; i < 3; ++i)
          #pragma unroll
          for (int kt = 0; kt < 4; ++kt)
            #pragma unroll
            for (int j = 0; j < 8; ++j) {
                int k = 32 * kt + 8 * g + j;
                float v = (k < E_DIM) ? Win[k * G_DIM + 16 * (w + 4 * i) + c16] : 0.f;
                awin[i][kt][j] = (short)f2bf(v);
            }
        #pragma unroll
        for (int i = 0; i < 3; ++i)
          #pragma unroll
          for (int rr = 0; rr < 4; ++rr)
              binq[4 * i + rr] = bin[16 * (w + 4 * i) + 4 * g + rr];
        xrow  = x + (size_t)(row0 + c16) * (L_SEQ * E_DIM);
        xlane = xrow + 8 * g;
    } else {
        #pragma unroll
        for (int i = 0; i < 3; ++i)
          #pragma unroll
          for (int kt = 0; kt < 2; ++kt)
            #pragma unroll
            for (int j = 0; j < 8; ++j)
                awh[i][kt][j] = (short)f2bf(Wh[(32 * kt + 8 * g + j) * G_DIM + 16 * (w + 4 * i) + c16]);
        #pragma unroll
        for (int i = 0; i < 3; ++i)
          #pragma unroll
          for (int rr = 0; rr < 4; ++rr)
              bhq[4 * i + rr] = bh[16 * (w + 4 * i) + 4 * g + rr];
        // Gram fragments for u = M·h (A-layout, n-tiles 0..3)
        #pragma unroll
        for (int nt = 0; nt < 4; ++nt)
          #pragma unroll
          for (int kt = 0; kt < 2; ++kt)
            #pragma unroll
            for (int j = 0; j < 8; ++j)
                awm[nt][kt][j] = (short)f2bf(Ms[32 * kt + 8 * g + j][16 * nt + c16]);
        #pragma unroll
        for (int q = 0; q < 8; ++q) {
            wsumq[q]     = wsumS[8 * g + q];
            wsumq[8 + q] = wsumS[32 + 8 * g + q];
        }
        // C-preload for u-chain: 2*v at D-layout positions (dim 16nt+4g+rr)
        #pragma unroll
        for (int rr = 0; rr < 4; ++rr) {
            vC0[rr] = 2.f * vS[ 0 + 4 * g + rr];
            vC1[rr] = 2.f * vS[16 + 4 * g + rr];
            vC2[rr] = 2.f * vS[32 + 4 * g + rr];
            vC3[rr] = 2.f * vS[48 + 4 * g + rr];
        }
        sum_bh = sbhS[0];
        ssq_bh = sbhS[1];
        bf16x8 z = {0, 0, 0, 0, 0, 0, 0, 0};
        *(bf16x8*)&hs[0][c16][8 * g]      = z;
        *(bf16x8*)&hs[0][c16][32 + 8 * g] = z;
    }

    float* tird        = &tir[0][w][c16][g * 12];
    float* sltiw       = &slti[0][c16][2 * w];
    float* slthw       = &slth[0][c16][2 * w];
    const float* sltir = &slti[0][c16][0];

    float hreg[4] = {0.f, 0.f, 0.f, 0.f};

    XBuf xA, xB;
    if (tirole) {
        x_pf(xA, xlane, xrow, 0, g0);
        x_pf(xB, xlane, xrow, 1, g0);
        produce(xA, xlane, xrow, 0, g0, tird, sltiw, awin, binq);   // slot 0; refills xA for c=2
    }
    BAR();
    if (!tirole) __builtin_amdgcn_s_setprio(1);   // favor recurrent critical path (T5)

    auto HGEMM = [&](int par, float (&b)[12]) {
        bf16x8 h0 = *(const bf16x8*)&hs[par][c16][8 * g];
        bf16x8 h1 = *(const bf16x8*)&hs[par][c16][32 + 8 * g];
        const f32x4 zero = {0.f, 0.f, 0.f, 0.f};
        f32x4 t0 = MFMA16(awh[0][0], h0, zero, 0, 0, 0);
        f32x4 t1 = MFMA16(awh[1][0], h0, zero, 0, 0, 0);
        f32x4 t2 = MFMA16(awh[2][0], h0, zero, 0, 0, 0);
        t0 = MFMA16(awh[0][1], h1, t0, 0, 0, 0);
        t1 = MFMA16(awh[1][1], h1, t1, 0, 0, 0);
        t2 = MFMA16(awh[2][1], h1, t2, 0, 0, 0);
        #pragma unroll
        for (int rr = 0; rr < 4; ++rr) {
            b[rr]     = t0[rr] + bhq[rr];
            b[4 + rr] = t1[rr] + bhq[4 + rr];
            b[8 + rr] = t2[rr] + bhq[8 + rr];
        }
    };
    auto HWRITE = [&](int par, float (&hn)[4]) {
        *(uint2v*)&hs[par ^ 1][c16][16 * w + 4 * g] = (uint2v){cvtpk(hn[0], hn[1]), cvtpk(hn[2], hn[3])};
    };

    // phase-1 h-wave step: gates without norm (R8 verbatim)
    auto H1 = [&](int st) {
        const int par = st & 1;
        const float* src = tird + par * 3328;
        float4v a0 = *(const float4v*)(src);
        float4v a1 = *(const float4v*)(src + 4);
        float4v a2 = *(const float4v*)(src + 8);
        float b[12];
        HGEMM(par, b);
        float hn[4];
        #pragma unroll
        for (int rr = 0; rr < 4; ++rr) {
            float er = rcpf_(1.f + __expf(-(a0[rr] + b[rr])));
            float zt = rcpf_(1.f + __expf(-(a1[rr] + b[4 + rr])));
            float u  = fmaf(er, b[8 + rr], a2[rr]);
            float tn = fmaf(2.f, rcpf_(1.f + __expf(-2.f * u)), -1.f);
            hn[rr] = fmaf(zt, hreg[rr] - tn, tn);
            hreg[rr] = hn[rr];
        }
        HWRITE(par, hn);
    };

    // ---------------- phase 1: 1 barrier/step ----------------
    #pragma unroll 1
    for (int s = 0; s < L_SEQ; s += 2) {
        if (tirole) produce(xB, xlane, xrow, s + 1, g0, tird, sltiw, awin, binq);
        else        H1(s);
        BAR();
        if (tirole) produce(xA, xlane, xrow, s + 2, g0, tird, sltiw, awin, binq);
        else        H1(s + 1);
        BAR();
    }

    // phase-2 h-wave step: th stats via {wsum-dot + Gram quadratic form + bias terms} — NO mid-barrier
    auto H2 = [&](int st) {
        const int par = st & 1;
        const float* src = tird + par * 3328;
        float4v a0 = *(const float4v*)(src);
        float4v a1 = *(const float4v*)(src + 4);
        float4v a2 = *(const float4v*)(src + 8);
        const float* ip = sltir + par * 192;
        float4v r0 = *(const float4v*)(ip);
        float4v r1 = *(const float4v*)(ip + 4);
        float Sti  = (r0[0] + r0[2]) + (r1[0] + r1[2]);
        float SSti = (r0[1] + r0[3]) + (r1[1] + r1[3]);
        float mti  = Sti * (1.f / G_DIM);
        float vti  = (SSti - (float)G_DIM * mti * mti) * (1.f / (G_DIM - 1));
        float rti  = __builtin_amdgcn_rsqf(fmaxf(vti, 1e-24f));

        bf16x8 h0 = *(const bf16x8*)&hs[par][c16][8 * g];
        bf16x8 h1 = *(const bf16x8*)&hs[par][c16][32 + 8 * g];
        ushort4v hq0 = *(const ushort4v*)&hs[par][c16][4 * g];
        ushort4v hq1 = *(const ushort4v*)&hs[par][c16][16 + 4 * g];
        ushort4v hq2 = *(const ushort4v*)&hs[par][c16][32 + 4 * g];
        ushort4v hq3 = *(const ushort4v*)&hs[par][c16][48 + 4 * g];
        const f32x4 zero = {0.f, 0.f, 0.f, 0.f};
        // th quarter (own gates)
        f32x4 t0 = MFMA16(awh[0][0], h0, zero, 0, 0, 0);
        f32x4 t1 = MFMA16(awh[1][0], h0, zero, 0, 0, 0);
        f32x4 t2 = MFMA16(awh[2][0], h0, zero, 0, 0, 0);
        t0 = MFMA16(awh[0][1], h1, t0, 0, 0, 0);
        t1 = MFMA16(awh[1][1], h1, t1, 0, 0, 0);
        t2 = MFMA16(awh[2][1], h1, t2, 0, 0, 0);
        // u = M·h + 2v  (C-in carries 2v -> dot(h,u) = h^T M h + 2 dot(h,v))
        f32x4 u0 = MFMA16(awm[0][0], h0, vC0, 0, 0, 0);
        f32x4 u1 = MFMA16(awm[1][0], h0, vC1, 0, 0, 0);
        f32x4 u2 = MFMA16(awm[2][0], h0, vC2, 0, 0, 0);
        f32x4 u3 = MFMA16(awm[3][0], h0, vC3, 0, 0, 0);
        u0 = MFMA16(awm[0][1], h1, u0, 0, 0, 0);
        u1 = MFMA16(awm[1][1], h1, u1, 0, 0, 0);
        u2 = MFMA16(awm[2][1], h1, u2, 0, 0, 0);
        u3 = MFMA16(awm[3][1], h1, u3, 0, 0, 0);

        float b[12];
        #pragma unroll
        for (int rr = 0; rr < 4; ++rr) {
            b[rr]     = t0[rr] + bhq[rr];
            b[4 + rr] = t1[rr] + bhq[4 + rr];
            b[8 + rr] = t2[rr] + bhq[8 + rr];
        }
        // S partial = dot(h, rowsum(Wh)) over this lane's 16 h-dims
        float sS = 0.f;
        #pragma unroll
        for (int q = 0; q < 8; ++q) {
            sS = fmaf(bf2f((unsigned short)h0[q]), wsumq[q],     sS);
            sS = fmaf(bf2f((unsigned short)h1[q]), wsumq[8 + q], sS);
        }
        // SS partial = dot(h, u) over this lane's 16 u-dims (dims 16nt+4g+rr)
        float sSS = 0.f;
        #pragma unroll
        for (int rr = 0; rr < 4; ++rr) {
            sSS = fmaf(bf2f(hq0[rr]), u0[rr], sSS);
            sSS = fmaf(bf2f(hq1[rr]), u1[rr], sSS);
            sSS = fmaf(bf2f(hq2[rr]), u2[rr], sSS);
            sSS = fmaf(bf2f(hq3[rr]), u3[rr], sSS);
        }
        sS  += __shfl_xor(sS, 16);  sS  += __shfl_xor(sS, 32);
        sSS += __shfl_xor(sSS, 16); sSS += __shfl_xor(sSS, 32);
        float S   = sS + sum_bh;
        float SSf = sSS + ssq_bh;
        float mth = S * (1.f / G_DIM);
        float var = (SSf - (float)G_DIM * mth * mth) * (1.f / (G_DIM - 1));
        float rth = __builtin_amdgcn_rsqf(fmaxf(var, 1e-24f));

        float mrti = mti * rti, mrth = mth * rth;
        float Cn = mrti + mrth;
        float hn[4];
        #pragma unroll
        for (int rr = 0; rr < 4; ++rr) {
            float mr = fmaf(a0[rr], -rti, fmaf(b[rr],     -rth, Cn));
            float er = rcpf_(1.f + __expf(mr));
            float mz = fmaf(a1[rr], -rti, fmaf(b[4 + rr], -rth, Cn));
            float zt = rcpf_(1.f + __expf(mz));
            float ni = fmaf(a2[rr],     rti, -mrti);
            float nh = fmaf(b[8 + rr],  rth, -mrth);
            float u  = fmaf(er, nh, ni);
            float tn = fmaf(2.f, rcpf_(1.f + __expf(-2.f * u)), -1.f);
            hn[rr] = fmaf(zt, hreg[rr] - tn, tn);
            hreg[rr] = hn[rr];
        }
        HWRITE(par, hn);
    };

    // ---------------- phase 2: 1 barrier/step (mid-barrier eliminated) ----------------
    #pragma unroll 1
    for (int s = L_SEQ; s < 2 * L_SEQ; s += 2) {
        if (tirole) produce(xB, xlane, xrow, s + 1, g0, tird, sltiw, awin, binq);
        else        H2(s);
        BAR();
        if (tirole) produce(xA, xlane, xrow, s + 2, g0, tird, sltiw, awin, binq);
        else        H2(s + 1);
        BAR();
    }

    // ---------------- epilogue: out = h @ W_fc + b_fc ----------------
    if (!tirole) {
        float po0 = 0.f, po1 = 0.f;
        #pragma unroll
        for (int rr = 0; rr < 4; ++rr) {
            int c = 16 * w + 4 * g + rr;
            po0 = fmaf(hreg[rr], Wfc[2 * c],     po0);
            po1 = fmaf(hreg[rr], Wfc[2 * c + 1], po1);
        }
        po0 += __shfl_xor(po0, 16); po0 += __shfl_xor(po0, 32);
        po1 += __shfl_xor(po1, 16); po1 += __shfl_xor(po1, 32);
        if (g0) *(float2v*)(slthw) = (float2v){po0, po1};
    }
    BAR();
    if (tid < 16) {
        const float* sp = &slth[0][tid][0];
        float4v q0 = *(const float4v*)(sp);
        float4v q1 = *(const float4v*)(sp + 4);
        out[(row0 + tid) * 2 + 0] = (q0[0] + q0[2]) + (q1[0] + q1[2]) + bfc[0];
        out[(row0 + tid) * 2 + 1] = (q0[1] + q0[3]) + (q1[1] + q1[3]) + bfc[1];
    }
}

extern "C" void kernel_launch(void* const* d_in, const int* in_sizes, int n_in,
                              void* d_out, int out_size, void* d_ws, size_t ws_size,
                              hipStream_t stream) {
    const float* x   = (const float*)d_in[0];
    const float* Win = (const float*)d_in[1];
    const float* bin = (const float*)d_in[2];
    const float* Wh  = (const float*)d_in[3];
    const float* bh  = (const float*)d_in[4];
    const float* Wfc = (const float*)d_in[5];
    const float* bfc = (const float*)d_in[6];
    float* out = (float*)d_out;
    gru_ws<<<dim3(B_TOT / 16), dim3(512), 0, stream>>>(
        x, Win, bin, Wh, bh, Wfc, bfc, out);
}

// Round 15
// 200.693 us; speedup vs baseline: 7.9252x; 2.1558x over previous
//
#include <hip/hip_runtime.h>

#define L_SEQ 100
#define E_DIM 100
#define G_DIM 192   // 3*H
#define B_TOT 4096

typedef __attribute__((ext_vector_type(8))) short bf16x8;
typedef __attribute__((ext_vector_type(4))) float f32x4;
typedef __attribute__((ext_vector_type(4))) float float4v;
typedef __attribute__((ext_vector_type(2))) float float2v;
typedef __attribute__((ext_vector_type(4))) unsigned uint4v;
typedef __attribute__((ext_vector_type(2))) unsigned uint2v;

#define MFMA16 __builtin_amdgcn_mfma_f32_16x16x32_bf16

static __device__ __forceinline__ unsigned short f2bf(float f) {
    union { float f; unsigned u; } v; v.f = f;
    unsigned r = v.u + 0x7FFFu + ((v.u >> 16) & 1u);  // RNE
    return (unsigned short)(r >> 16);
}
static __device__ __forceinline__ unsigned cvtpk(float lo, float hi) {
    unsigned r;
    asm("v_cvt_pk_bf16_f32 %0, %1, %2" : "=v"(r) : "v"(lo), "v"(hi));
    return r;
}
static __device__ __forceinline__ bf16x8 as_bf16x8(uint4v u) {
    union { uint4v u; bf16x8 h; } v; v.u = u; return v.h;
}
static __device__ __forceinline__ float rcpf_(float x) { return __builtin_amdgcn_rcpf(x); }

// raw barrier: drains LDS ops only (keeps global prefetch in flight — no vmcnt drain)
#define BAR() do { \
    asm volatile("s_waitcnt lgkmcnt(0)" ::: "memory"); \
    __builtin_amdgcn_s_barrier(); \
    asm volatile("" ::: "memory"); \
} while (0)

struct XBuf { f32x4 v[6]; f32x4 tail; };

static __device__ __forceinline__ int tmod(int c) {
    int t = c;
    if (t >= L_SEQ) t -= L_SEQ;
    if (t >= L_SEQ) t -= L_SEQ;
    return t;
}

static __device__ __forceinline__ void x_pf(
    XBuf& b, const float* __restrict__ xlane, const float* __restrict__ xrow, int c, bool g0)
{
    const int t = tmod(c);
    const float* p = xlane + t * E_DIM;
    b.v[0] = *(const f32x4*)(p);
    b.v[1] = *(const f32x4*)(p + 4);
    b.v[2] = *(const f32x4*)(p + 32);
    b.v[3] = *(const f32x4*)(p + 36);
    b.v[4] = *(const f32x4*)(p + 64);
    b.v[5] = *(const f32x4*)(p + 68);
    const f32x4 z = {0.f, 0.f, 0.f, 0.f};
    b.tail = g0 ? *(const f32x4*)(xrow + t * E_DIM + 96) : z;
}

// ti-wave: compute ti[c] = x[c]@Win + bin, write to LDS ring + stat partials
static __device__ __forceinline__ void produce(
    XBuf& xb, const float* __restrict__ xlane, const float* __restrict__ xrow,
    int c, bool g0, float* __restrict__ tird, float* __restrict__ sltiw,
    const bf16x8 (&awin)[3][4], const float (&binq)[12])
{
    bf16x8 bx0 = as_bf16x8((uint4v){cvtpk(xb.v[0][0], xb.v[0][1]), cvtpk(xb.v[0][2], xb.v[0][3]),
                                    cvtpk(xb.v[1][0], xb.v[1][1]), cvtpk(xb.v[1][2], xb.v[1][3])});
    bf16x8 bx1 = as_bf16x8((uint4v){cvtpk(xb.v[2][0], xb.v[2][1]), cvtpk(xb.v[2][2], xb.v[2][3]),
                                    cvtpk(xb.v[3][0], xb.v[3][1]), cvtpk(xb.v[3][2], xb.v[3][3])});
    bf16x8 bx2 = as_bf16x8((uint4v){cvtpk(xb.v[4][0], xb.v[4][1]), cvtpk(xb.v[4][2], xb.v[4][3]),
                                    cvtpk(xb.v[5][0], xb.v[5][1]), cvtpk(xb.v[5][2], xb.v[5][3])});
    bf16x8 bx3 = as_bf16x8((uint4v){cvtpk(xb.tail[0], xb.tail[1]), cvtpk(xb.tail[2], xb.tail[3]),
                                    0u, 0u});
    x_pf(xb, xlane, xrow, c + 2, g0);   // reissue this buffer 2 steps ahead

    const f32x4 zero = {0.f, 0.f, 0.f, 0.f};
    f32x4 t0 = MFMA16(awin[0][0], bx0, zero, 0, 0, 0);
    f32x4 t1 = MFMA16(awin[1][0], bx0, zero, 0, 0, 0);
    f32x4 t2 = MFMA16(awin[2][0], bx0, zero, 0, 0, 0);
    t0 = MFMA16(awin[0][1], bx1, t0, 0, 0, 0);
    t1 = MFMA16(awin[1][1], bx1, t1, 0, 0, 0);
    t2 = MFMA16(awin[2][1], bx1, t2, 0, 0, 0);
    t0 = MFMA16(awin[0][2], bx2, t0, 0, 0, 0);
    t1 = MFMA16(awin[1][2], bx2, t1, 0, 0, 0);
    t2 = MFMA16(awin[2][2], bx2, t2, 0, 0, 0);
    t0 = MFMA16(awin[0][3], bx3, t0, 0, 0, 0);
    t1 = MFMA16(awin[1][3], bx3, t1, 0, 0, 0);
    t2 = MFMA16(awin[2][3], bx3, t2, 0, 0, 0);

    const int par = c & 1;
    float4v A0 = {t0[0] + binq[0], t0[1] + binq[1], t0[2] + binq[2],  t0[3] + binq[3]};
    float4v A1 = {t1[0] + binq[4], t1[1] + binq[5], t1[2] + binq[6],  t1[3] + binq[7]};
    float4v A2 = {t2[0] + binq[8], t2[1] + binq[9], t2[2] + binq[10], t2[3] + binq[11]};
    float* dst = tird + par * 3328;     // parity stride = 4*16*52 floats
    *(float4v*)(dst)     = A0;
    *(float4v*)(dst + 4) = A1;
    *(float4v*)(dst + 8) = A2;

    float s = ((A0[0] + A0[1]) + (A0[2] + A0[3])) + ((A1[0] + A1[1]) + (A1[2] + A1[3]))
            + ((A2[0] + A2[1]) + (A2[2] + A2[3]));
    float ss = 0.f;
    #pragma unroll
    for (int k2 = 0; k2 < 4; ++k2) ss = fmaf(A0[k2], A0[k2], ss);
    #pragma unroll
    for (int k2 = 0; k2 < 4; ++k2) ss = fmaf(A1[k2], A1[k2], ss);
    #pragma unroll
    for (int k2 = 0; k2 < 4; ++k2) ss = fmaf(A2[k2], A2[k2], ss);
    s  += __shfl_xor(s, 16);  s  += __shfl_xor(s, 32);
    ss += __shfl_xor(ss, 16); ss += __shfl_xor(ss, 32);
    if (g0) *(float2v*)(sltiw + par * 192) = (float2v){s, ss};
}

__global__ __launch_bounds__(512, 1) void gru_ws(
    const float* __restrict__ x,
    const float* __restrict__ Win, const float* __restrict__ bin,
    const float* __restrict__ Wh,  const float* __restrict__ bh,
    const float* __restrict__ Wfc, const float* __restrict__ bfc,
    float* __restrict__ out)
{
    __shared__ __align__(16) unsigned short hs[2][16][72];   // h ring [parity][row][hdim]
    __shared__ __align__(16) float tir[2][4][16][52];        // ti ring [parity][w][row][g*12+i*4+rr]
    __shared__ __align__(16) float slti[2][16][12];          // ti stat partials {s,ss} per wave
    __shared__ __align__(16) float slth[2][16][12];          // th stat partials

    const int tid = threadIdx.x;
    const int wv  = tid >> 6;
    const int w   = wv & 3;                 // role-local wave index (ntg group)
    const bool tirole = (wv >= 4);
    const int l = tid & 63, c16 = l & 15, g = l >> 4;
    const bool g0 = (g == 0);
    const int row0 = blockIdx.x * 16;

    bf16x8 awin[3][4]; float binq[12];
    bf16x8 awh[3][2];  float bhq[12];
    const float* xrow = nullptr; const float* xlane = nullptr;

    if (tirole) {
        #pragma unroll
        for (int i = 0; i < 3; ++i)
          #pragma unroll
          for (int kt = 0; kt < 4; ++kt)
            #pragma unroll
            for (int j = 0; j < 8; ++j) {
                int k = 32 * kt + 8 * g + j;
                float v = (k < E_DIM) ? Win[k * G_DIM + 16 * (w + 4 * i) + c16] : 0.f;
                awin[i][kt][j] = (short)f2bf(v);
            }
        #pragma unroll
        for (int i = 0; i < 3; ++i)
          #pragma unroll
          for (int rr = 0; rr < 4; ++rr)
              binq[4 * i + rr] = bin[16 * (w + 4 * i) + 4 * g + rr];
        xrow  = x + (size_t)(row0 + c16) * (L_SEQ * E_DIM);
        xlane = xrow + 8 * g;
    } else {
        #pragma unroll
        for (int i = 0; i < 3; ++i)
          #pragma unroll
          for (int kt = 0; kt < 2; ++kt)
            #pragma unroll
            for (int j = 0; j < 8; ++j)
                awh[i][kt][j] = (short)f2bf(Wh[(32 * kt + 8 * g + j) * G_DIM + 16 * (w + 4 * i) + c16]);
        #pragma unroll
        for (int i = 0; i < 3; ++i)
          #pragma unroll
          for (int rr = 0; rr < 4; ++rr)
              bhq[4 * i + rr] = bh[16 * (w + 4 * i) + 4 * g + rr];
        bf16x8 z = {0, 0, 0, 0, 0, 0, 0, 0};
        *(bf16x8*)&hs[0][c16][8 * g]      = z;
        *(bf16x8*)&hs[0][c16][32 + 8 * g] = z;
    }

    float* tird        = &tir[0][w][c16][g * 12];
    float* sltiw       = &slti[0][c16][2 * w];
    float* slthw       = &slth[0][c16][2 * w];
    const float* sltir = &slti[0][c16][0];
    const float* slthr = &slth[0][c16][0];

    float hreg[4] = {0.f, 0.f, 0.f, 0.f};

    XBuf xA, xB;
    if (tirole) {
        x_pf(xA, xlane, xrow, 0, g0);
        x_pf(xB, xlane, xrow, 1, g0);
        produce(xA, xlane, xrow, 0, g0, tird, sltiw, awin, binq);   // ti[0]; reissues A for c=2
    }
    BAR();
    if (!tirole) __builtin_amdgcn_s_setprio(1);   // favor the recurrent critical path (T5)

    auto HGEMM = [&](int par, float4v& a0, float4v& a1, float4v& a2, float (&b)[12]) {
        const float* src = tird + par * 3328;
        a0 = *(const float4v*)(src);
        a1 = *(const float4v*)(src + 4);
        a2 = *(const float4v*)(src + 8);
        bf16x8 h0 = *(const bf16x8*)&hs[par][c16][8 * g];
        bf16x8 h1 = *(const bf16x8*)&hs[par][c16][32 + 8 * g];
        const f32x4 zero = {0.f, 0.f, 0.f, 0.f};
        f32x4 t0 = MFMA16(awh[0][0], h0, zero, 0, 0, 0);
        f32x4 t1 = MFMA16(awh[1][0], h0, zero, 0, 0, 0);
        f32x4 t2 = MFMA16(awh[2][0], h0, zero, 0, 0, 0);
        t0 = MFMA16(awh[0][1], h1, t0, 0, 0, 0);
        t1 = MFMA16(awh[1][1], h1, t1, 0, 0, 0);
        t2 = MFMA16(awh[2][1], h1, t2, 0, 0, 0);
        #pragma unroll
        for (int rr = 0; rr < 4; ++rr) {
            b[rr]     = t0[rr] + bhq[rr];
            b[4 + rr] = t1[rr] + bhq[4 + rr];
            b[8 + rr] = t2[rr] + bhq[8 + rr];
        }
    };
    auto HWRITE = [&](int par, float (&hn)[4]) {
        *(uint2v*)&hs[par ^ 1][c16][16 * w + 4 * g] = (uint2v){cvtpk(hn[0], hn[1]), cvtpk(hn[2], hn[3])};
    };

    // ---------------- phase 1: no norm, 1 barrier/step ----------------
    #pragma unroll 1
    for (int s = 0; s < L_SEQ; s += 2) {
        #pragma unroll
        for (int sub = 0; sub < 2; ++sub) {
            const int st = s + sub;
            XBuf& X = sub ? xA : xB;
            if (tirole) {
                produce(X, xlane, xrow, st + 1, g0, tird, sltiw, awin, binq);
            } else {
                const int par = st & 1;
                float4v a0, a1, a2; float b[12];
                HGEMM(par, a0, a1, a2, b);
                float hn[4];
                #pragma unroll
                for (int rr = 0; rr < 4; ++rr) {
                    float er = rcpf_(1.f + __expf(-(a0[rr] + b[rr])));
                    float zt = rcpf_(1.f + __expf(-(a1[rr] + b[4 + rr])));
                    float u  = fmaf(er, b[8 + rr], a2[rr]);
                    float tn = fmaf(2.f, rcpf_(1.f + __expf(-2.f * u)), -1.f);
                    hn[rr] = fmaf(zt, hreg[rr] - tn, tn);
                    hreg[rr] = hn[rr];
                }
                HWRITE(par, hn);
            }
            BAR();
        }
    }

    // ---------------- phase 2: vector norm, 2 barriers/step ----------------
    #pragma unroll 1
    for (int s = L_SEQ; s < 2 * L_SEQ; s += 2) {
        #pragma unroll
        for (int sub = 0; sub < 2; ++sub) {
            const int st = s + sub;
            XBuf& X = sub ? xA : xB;
            const int par = st & 1;
            float4v a0, a1, a2; float b[12];
            if (tirole) {
                produce(X, xlane, xrow, st + 1, g0, tird, sltiw, awin, binq);
            } else {
                HGEMM(par, a0, a1, a2, b);
                float sb = 0.f, ssb = 0.f;
                #pragma unroll
                for (int k2 = 0; k2 < 12; ++k2) { sb += b[k2]; ssb = fmaf(b[k2], b[k2], ssb); }
                sb  += __shfl_xor(sb, 16);  sb  += __shfl_xor(sb, 32);
                ssb += __shfl_xor(ssb, 16); ssb += __shfl_xor(ssb, 32);
                if (g0) *(float2v*)(slthw + par * 192) = (float2v){sb, ssb};
            }
            BAR();   // mid: th partials visible (ti stats were published a step earlier)
            if (!tirole) {
                const float* sp = slthr + par * 192;
                float4v q0 = *(const float4v*)(sp);
                float4v q1 = *(const float4v*)(sp + 4);
                const float* ip = sltir + par * 192;
                float4v r0 = *(const float4v*)(ip);
                float4v r1 = *(const float4v*)(ip + 4);
                float Sth  = (q0[0] + q0[2]) + (q1[0] + q1[2]);
                float SSth = (q0[1] + q0[3]) + (q1[1] + q1[3]);
                float Sti  = (r0[0] + r0[2]) + (r1[0] + r1[2]);
                float SSti = (r0[1] + r0[3]) + (r1[1] + r1[3]);
                float mth = Sth * (1.f / G_DIM);
                float rth = __builtin_amdgcn_rsqf(
                    fmaxf((SSth - (float)G_DIM * mth * mth) * (1.f / (G_DIM - 1)), 1e-24f));
                float mti = Sti * (1.f / G_DIM);
                float rti = __builtin_amdgcn_rsqf(
                    fmaxf((SSti - (float)G_DIM * mti * mti) * (1.f / (G_DIM - 1)), 1e-24f));
                float mrti = mti * rti, mrth = mth * rth;
                float Cn = mrti + mrth;   // sigmoid arg: -x = -a*rti - b*rth + Cn (2 fma)
                float hn[4];
                #pragma unroll
                for (int rr = 0; rr < 4; ++rr) {
                    float mr = fmaf(a0[rr], -rti, fmaf(b[rr],     -rth, Cn));
                    float er = rcpf_(1.f + __expf(mr));
                    float mz = fmaf(a1[rr], -rti, fmaf(b[4 + rr], -rth, Cn));
                    float zt = rcpf_(1.f + __expf(mz));
                    float ni = fmaf(a2[rr],     rti, -mrti);
                    float nh = fmaf(b[8 + rr],  rth, -mrth);
                    float u  = fmaf(er, nh, ni);
                    float tn = fmaf(2.f, rcpf_(1.f + __expf(-2.f * u)), -1.f);
                    hn[rr] = fmaf(zt, hreg[rr] - tn, tn);
                    hreg[rr] = hn[rr];
                }
                HWRITE(par, hn);
            }
            BAR();   // end: h' visible
        }
    }

    // ---------------- epilogue: out = h @ W_fc + b_fc ----------------
    if (!tirole) {
        float po0 = 0.f, po1 = 0.f;
        #pragma unroll
        for (int rr = 0; rr < 4; ++rr) {
            int c = 16 * w + 4 * g + rr;
            po0 = fmaf(hreg[rr], Wfc[2 * c],     po0);
            po1 = fmaf(hreg[rr], Wfc[2 * c + 1], po1);
        }
        po0 += __shfl_xor(po0, 16); po0 += __shfl_xor(po0, 32);
        po1 += __shfl_xor(po1, 16); po1 += __shfl_xor(po1, 32);
        if (g0) *(float2v*)(slthw) = (float2v){po0, po1};
    }
    BAR();
    if (tid < 16) {
        const float* sp = &slth[0][tid][0];
        float4v q0 = *(const float4v*)(sp);
        float4v q1 = *(const float4v*)(sp + 4);
        out[(row0 + tid) * 2 + 0] = (q0[0] + q0[2]) + (q1[0] + q1[2]) + bfc[0];
        out[(row0 + tid) * 2 + 1] = (q0[1] + q0[3]) + (q1[1] + q1[3]) + bfc[1];
    }
}

extern "C" void kernel_launch(void* const* d_in, const int* in_sizes, int n_in,
                              void* d_out, int out_size, void* d_ws, size_t ws_size,
                              hipStream_t stream) {
    const float* x   = (const float*)d_in[0];
    const float* Win = (const float*)d_in[1];
    const float* bin = (const float*)d_in[2];
    const float* Wh  = (const float*)d_in[3];
    const float* bh  = (const float*)d_in[4];
    const float* Wfc = (const float*)d_in[5];
    const float* bfc = (const float*)d_in[6];
    float* out = (float*)d_out;
    gru_ws<<<dim3(B_TOT / 16), dim3(512), 0, stream>>>(
        x, Win, bin, Wh, bh, Wfc, bfc, out);
}